// Round 1
// baseline (4250.747 us; speedup 1.0000x reference)
//
#include <hip/hip_runtime.h>

#define N_NODES 50000
#define N_GRAPHS 500
#define E_SPARSE 800000
#define E_DENSE 3200000
#define IN_DIM 128
#define HID 128
#define OUT_D 64
#define N_LAYERS 3
#define NEG_SLOPE 0.2f

// Order-preserving encoding of float into uint32 for atomicMax
__device__ __forceinline__ unsigned enc_f(float f) {
    unsigned u = __float_as_uint(f);
    return (u & 0x80000000u) ? ~u : (u | 0x80000000u);
}
__device__ __forceinline__ float dec_f(unsigned u) {
    return (u & 0x80000000u) ? __uint_as_float(u & 0x7FFFFFFFu)
                             : __uint_as_float(~u);
}

// One block (64 threads) per node: h[node][j] = dot(x[node,:], W[:,j]),
// then wave-reduce s_src / s_dst.
__global__ void node_mm(const float* __restrict__ x, const float* __restrict__ W,
                        const float* __restrict__ a_s, const float* __restrict__ a_d,
                        float* __restrict__ h, float* __restrict__ s_src,
                        float* __restrict__ s_dst) {
    int node = blockIdx.x;
    int j = threadIdx.x;  // 0..63
    __shared__ float xs[IN_DIM];
    const float* xr = x + (size_t)node * IN_DIM;
    xs[j] = xr[j];
    xs[j + 64] = xr[j + 64];
    __syncthreads();
    float acc = 0.f;
#pragma unroll 8
    for (int k = 0; k < IN_DIM; ++k) acc += xs[k] * W[k * OUT_D + j];
    h[(size_t)node * OUT_D + j] = acc;
    float ps = acc * a_s[j];
    float pd = acc * a_d[j];
    for (int off = 32; off > 0; off >>= 1) {
        ps += __shfl_down(ps, off);
        pd += __shfl_down(pd, off);
    }
    if (j == 0) { s_src[node] = ps; s_dst[node] = pd; }
}

// Pass 1: e = leakyrelu(s_src[src]+s_dst[dst]); atomicMax into m_enc[dst]
__global__ void edge_scores(const int* __restrict__ src, const int* __restrict__ dst,
                            int E, const float* __restrict__ s_src,
                            const float* __restrict__ s_dst,
                            float* __restrict__ ebuf, unsigned* __restrict__ menc) {
    int i = blockIdx.x * blockDim.x + threadIdx.x;
    int tot = E + N_NODES;
    if (i >= tot) return;
    int s, d;
    if (i < E) { s = src[i]; d = dst[i]; } else { s = i - E; d = s; }
    float e = s_src[s] + s_dst[d];
    e = (e >= 0.f) ? e : NEG_SLOPE * e;
    ebuf[i] = e;
    atomicMax(menc + d, enc_f(e));
}

// Pass 2: p = exp(e - m[dst]); atomicAdd into z[dst]
__global__ void edge_exp(const int* __restrict__ dst, int E,
                         const unsigned* __restrict__ menc,
                         float* __restrict__ ebuf, float* __restrict__ z) {
    int i = blockIdx.x * blockDim.x + threadIdx.x;
    int tot = E + N_NODES;
    if (i >= tot) return;
    int d = (i < E) ? dst[i] : (i - E);
    float p = expf(ebuf[i] - dec_f(menc[d]));
    ebuf[i] = p;
    atomicAdd(z + d, p);
}

// Pass 3: out[dst][j] += (p/z[dst]) * h[src][j]; one thread per (edge, j)
__global__ void edge_aggr(const int* __restrict__ src, const int* __restrict__ dst,
                          int E, const float* __restrict__ ebuf,
                          const float* __restrict__ z, const float* __restrict__ h,
                          float* __restrict__ xnext, int col_off) {
    long long i = (long long)blockIdx.x * blockDim.x + threadIdx.x;
    long long tot = (long long)(E + N_NODES) * OUT_D;
    if (i >= tot) return;
    int e = (int)(i >> 6);
    int j = (int)(i & 63);
    int s, d;
    if (e < E) { s = src[e]; d = dst[e]; } else { s = e - E; d = s; }
    float w = ebuf[e] / z[d];
    atomicAdd(xnext + (size_t)d * HID + col_off + j, w * h[(size_t)s * OUT_D + j]);
}

// bias + relu in-place over [N_NODES, HID]
__global__ void finalize_layer(float* __restrict__ xnext, const float* __restrict__ bias) {
    int i = blockIdx.x * blockDim.x + threadIdx.x;
    if (i >= N_NODES * HID) return;
    float v = xnext[i] + bias[i & 63];
    xnext[i] = v > 0.f ? v : 0.f;
}

// global add pool: g[batch[node]][j] += x[node][j]
__global__ void pool(const float* __restrict__ x, const int* __restrict__ batch,
                     float* __restrict__ g) {
    int i = blockIdx.x * blockDim.x + threadIdx.x;
    if (i >= N_NODES * HID) return;
    int node = i >> 7;
    int j = i & 127;
    atomicAdd(g + (size_t)batch[node] * HID + j, x[i]);
}

// y[b] = dot(g[b,:], final_w) + final_b
__global__ void final_lin(const float* __restrict__ g, const float* __restrict__ fw,
                          const float* __restrict__ fb, float* __restrict__ y) {
    int b = blockIdx.x;
    int t = threadIdx.x;  // 0..127
    __shared__ float sm[HID];
    sm[t] = g[(size_t)b * HID + t] * fw[t];
    __syncthreads();
    for (int off = 64; off > 0; off >>= 1) {
        if (t < off) sm[t] += sm[t + off];
        __syncthreads();
    }
    if (t == 0) y[b] = sm[0] + fb[0];
}

extern "C" void kernel_launch(void* const* d_in, const int* in_sizes, int n_in,
                              void* d_out, int out_size, void* d_ws, size_t ws_size,
                              hipStream_t stream) {
    const float* x_in    = (const float*)d_in[0];
    const int*   ei      = (const int*)d_in[1];   // [2, E_SPARSE]
    const int*   di      = (const int*)d_in[2];   // [2, E_DENSE]
    const int*   batch   = (const int*)d_in[3];
    const float* lin_w   = (const float*)d_in[4]; // [3,128,64]
    const float* att_src = (const float*)d_in[5]; // [3,64]
    const float* att_dst = (const float*)d_in[6];
    const float* bias    = (const float*)d_in[7];
    const float* fw      = (const float*)d_in[8]; // [128,1]
    const float* fb      = (const float*)d_in[9];
    float* y = (float*)d_out;

    float* ws = (float*)d_ws;
    size_t off = 0;
    float* xbuf0 = ws + off; off += (size_t)N_NODES * HID;
    float* xbuf1 = ws + off; off += (size_t)N_NODES * HID;
    float* h     = ws + off; off += (size_t)N_NODES * OUT_D;
    float* s_src = ws + off; off += N_NODES;
    float* s_dst = ws + off; off += N_NODES;
    unsigned* menc = (unsigned*)(ws + off); off += N_NODES;
    float* z     = ws + off; off += N_NODES;
    float* ebuf  = ws + off; off += (size_t)(E_DENSE + N_NODES);
    float* g     = ws + off; off += (size_t)N_GRAPHS * HID;

    hipMemcpyAsync(xbuf0, x_in, sizeof(float) * (size_t)N_NODES * HID,
                   hipMemcpyDeviceToDevice, stream);

    float* xc = xbuf0;
    float* xn = xbuf1;
    for (int l = 0; l < N_LAYERS; ++l) {
        node_mm<<<N_NODES, 64, 0, stream>>>(xc, lin_w + (size_t)l * HID * OUT_D,
                                            att_src + l * OUT_D, att_dst + l * OUT_D,
                                            h, s_src, s_dst);
        hipMemsetAsync(xn, 0, sizeof(float) * (size_t)N_NODES * HID, stream);

        const int* srcs[2] = {ei, di};
        const int* dsts[2] = {ei + E_SPARSE, di + E_DENSE};
        const int  Es[2]   = {E_SPARSE, E_DENSE};
        const int  coff[2] = {0, OUT_D};
        for (int b = 0; b < 2; ++b) {
            hipMemsetAsync(menc, 0, sizeof(unsigned) * N_NODES, stream);
            hipMemsetAsync(z, 0, sizeof(float) * N_NODES, stream);
            int tot = Es[b] + N_NODES;
            int blks = (tot + 255) / 256;
            edge_scores<<<blks, 256, 0, stream>>>(srcs[b], dsts[b], Es[b],
                                                  s_src, s_dst, ebuf, menc);
            edge_exp<<<blks, 256, 0, stream>>>(dsts[b], Es[b], menc, ebuf, z);
            long long tt = (long long)tot * OUT_D;
            edge_aggr<<<(unsigned)((tt + 255) / 256), 256, 0, stream>>>(
                srcs[b], dsts[b], Es[b], ebuf, z, h, xn, coff[b]);
        }
        finalize_layer<<<(N_NODES * HID + 255) / 256, 256, 0, stream>>>(
            xn, bias + l * OUT_D);
        float* t = xc; xc = xn; xn = t;
    }

    hipMemsetAsync(g, 0, sizeof(float) * (size_t)N_GRAPHS * HID, stream);
    pool<<<(N_NODES * HID + 255) / 256, 256, 0, stream>>>(xc, batch, g);
    final_lin<<<N_GRAPHS, HID, 0, stream>>>(g, fw, fb, y);
}

// Round 2
// 1461.001 us; speedup vs baseline: 2.9095x; 2.9095x over previous
//
#include <hip/hip_runtime.h>

#define N_NODES 50000
#define N_GRAPHS 500
#define E_SPARSE 800000
#define E_DENSE 3200000
#define IN_DIM 128
#define HID 128
#define OUT_D 64
#define N_LAYERS 3
#define NEG_SLOPE 0.2f

// ---------------- CSR construction (per call; shared across layers) --------

__global__ void hist_kernel(const int* __restrict__ dst, int E, int* __restrict__ cnt) {
    int i = blockIdx.x * blockDim.x + threadIdx.x;
    if (i < E) atomicAdd(cnt + dst[i], 1);
}

// single-block scan: rowptr = exclusive_scan(cnt), cursor = copy of rowptr
__global__ void scan_kernel(const int* __restrict__ cnt, int n,
                            int* __restrict__ rowptr, int* __restrict__ cursor) {
    __shared__ int sm[1024];
    __shared__ int carry_s;
    int t = threadIdx.x;
    if (t == 0) carry_s = 0;
    __syncthreads();
    for (int base = 0; base < n; base += 1024) {
        int i = base + t;
        int v = (i < n) ? cnt[i] : 0;
        sm[t] = v;
        __syncthreads();
        for (int off = 1; off < 1024; off <<= 1) {
            int add = (t >= off) ? sm[t - off] : 0;
            __syncthreads();
            sm[t] += add;
            __syncthreads();
        }
        int excl = sm[t] - v + carry_s;
        if (i < n) { rowptr[i] = excl; cursor[i] = excl; }
        __syncthreads();
        if (t == 0) carry_s += sm[1023];
        __syncthreads();
    }
    if (t == 0) rowptr[n] = carry_s;
}

__global__ void scatter_kernel(const int* __restrict__ src, const int* __restrict__ dst,
                               int E, int* __restrict__ cursor, int* __restrict__ csrc) {
    int i = blockIdx.x * blockDim.x + threadIdx.x;
    if (i < E) {
        int p = atomicAdd(cursor + dst[i], 1);
        csrc[p] = src[i];
    }
}

// ---------------- per-layer kernels ----------------------------------------

// One wave (64 lanes) per node: h[node][j] = dot(x[node,:], W[:,j]),
// then wave-reduce s_src / s_dst.
__global__ void node_mm(const float* __restrict__ x, const float* __restrict__ W,
                        const float* __restrict__ a_s, const float* __restrict__ a_d,
                        float* __restrict__ h, float* __restrict__ s_src,
                        float* __restrict__ s_dst) {
    int node = blockIdx.x;
    int j = threadIdx.x;  // 0..63
    __shared__ float xs[IN_DIM];
    const float* xr = x + (size_t)node * IN_DIM;
    xs[j] = xr[j];
    xs[j + 64] = xr[j + 64];
    __syncthreads();
    float acc = 0.f;
#pragma unroll 8
    for (int k = 0; k < IN_DIM; ++k) acc += xs[k] * W[k * OUT_D + j];
    h[(size_t)node * OUT_D + j] = acc;
    float ps = acc * a_s[j];
    float pd = acc * a_d[j];
    for (int off = 32; off > 0; off >>= 1) {
        ps += __shfl_down(ps, off);
        pd += __shfl_down(pd, off);
    }
    if (j == 0) { s_src[node] = ps; s_dst[node] = pd; }
}

// Fused GAT aggregation: one wave per dst node. Self-loop handled implicitly.
// pass1: row max (lanes parallel over edges). pass2: serial edges, acc += p*h[src],
// z += p. out = relu(acc/z + bias).
__global__ __launch_bounds__(256) void gat_aggr(
    const int* __restrict__ rowptr, const int* __restrict__ csrc,
    const float* __restrict__ s_src, const float* __restrict__ s_dst,
    const float* __restrict__ h, const float* __restrict__ bias,
    float* __restrict__ xnext, int col_off) {
    int node = blockIdx.x * (blockDim.x >> 6) + (threadIdx.x >> 6);
    int lane = threadIdx.x & 63;
    if (node >= N_NODES) return;
    int beg = rowptr[node];
    int end = rowptr[node + 1];
    float sd = s_dst[node];
    float ss_self = s_src[node];

    // pass 1: max over edges + self-loop
    float e0 = ss_self + sd;
    float m = (e0 >= 0.f) ? e0 : NEG_SLOPE * e0;
    for (int k = beg + lane; k < end; k += 64) {
        float e = s_src[csrc[k]] + sd;
        e = (e >= 0.f) ? e : NEG_SLOPE * e;
        m = fmaxf(m, e);
    }
#pragma unroll
    for (int off = 32; off > 0; off >>= 1) m = fmaxf(m, __shfl_xor(m, off));

    // pass 2: serial accumulation (z identical across lanes)
    float es = ss_self + sd;
    es = (es >= 0.f) ? es : NEG_SLOPE * es;
    float p0 = __expf(es - m);
    float z = p0;
    float acc = p0 * h[(size_t)node * OUT_D + lane];
#pragma unroll 4
    for (int k = beg; k < end; ++k) {
        int s = csrc[k];
        float e = s_src[s] + sd;
        e = (e >= 0.f) ? e : NEG_SLOPE * e;
        float p = __expf(e - m);
        z += p;
        acc += p * h[(size_t)s * OUT_D + lane];
    }
    float v = acc / z + bias[lane];
    xnext[(size_t)node * HID + col_off + lane] = (v > 0.f) ? v : 0.f;
}

// global add pool: g[batch[node]][j] += x[node][j]
__global__ void pool(const float* __restrict__ x, const int* __restrict__ batch,
                     float* __restrict__ g) {
    int i = blockIdx.x * blockDim.x + threadIdx.x;
    if (i >= N_NODES * HID) return;
    int node = i >> 7;
    int j = i & 127;
    atomicAdd(g + (size_t)batch[node] * HID + j, x[i]);
}

// y[b] = dot(g[b,:], final_w) + final_b
__global__ void final_lin(const float* __restrict__ g, const float* __restrict__ fw,
                          const float* __restrict__ fb, float* __restrict__ y) {
    int b = blockIdx.x;
    int t = threadIdx.x;  // 0..127
    __shared__ float sm[HID];
    sm[t] = g[(size_t)b * HID + t] * fw[t];
    __syncthreads();
    for (int off = 64; off > 0; off >>= 1) {
        if (t < off) sm[t] += sm[t + off];
        __syncthreads();
    }
    if (t == 0) y[b] = sm[0] + fb[0];
}

extern "C" void kernel_launch(void* const* d_in, const int* in_sizes, int n_in,
                              void* d_out, int out_size, void* d_ws, size_t ws_size,
                              hipStream_t stream) {
    const float* x_in    = (const float*)d_in[0];
    const int*   ei      = (const int*)d_in[1];   // [2, E_SPARSE]
    const int*   di      = (const int*)d_in[2];   // [2, E_DENSE]
    const int*   batch   = (const int*)d_in[3];
    const float* lin_w   = (const float*)d_in[4]; // [3,128,64]
    const float* att_src = (const float*)d_in[5]; // [3,64]
    const float* att_dst = (const float*)d_in[6];
    const float* bias    = (const float*)d_in[7];
    const float* fw      = (const float*)d_in[8]; // [128,1]
    const float* fb      = (const float*)d_in[9];
    float* y = (float*)d_out;

    char* wsb = (char*)d_ws;
    size_t off = 0;
    auto alloc_f = [&](size_t n) { float* p = (float*)(wsb + off); off += n * 4; return p; };
    auto alloc_i = [&](size_t n) { int* p = (int*)(wsb + off); off += n * 4; return p; };

    float* xbuf0 = alloc_f((size_t)N_NODES * HID);
    float* xbuf1 = alloc_f((size_t)N_NODES * HID);
    float* h     = alloc_f((size_t)N_NODES * OUT_D);
    float* s_src = alloc_f(N_NODES);
    float* s_dst = alloc_f(N_NODES);
    float* g     = alloc_f((size_t)N_GRAPHS * HID);
    int* cntS    = alloc_i(N_NODES);
    int* rowS    = alloc_i(N_NODES + 1);
    int* curS    = alloc_i(N_NODES);
    int* csrcS   = alloc_i(E_SPARSE);
    int* cntD    = alloc_i(N_NODES);
    int* rowD    = alloc_i(N_NODES + 1);
    int* curD    = alloc_i(N_NODES);
    int* csrcD   = alloc_i(E_DENSE);

    const int* srcS = ei;
    const int* dstS = ei + E_SPARSE;
    const int* srcD = di;
    const int* dstD = di + E_DENSE;

    // ---- build CSR for both branches (reused across all 3 layers) ----
    hipMemsetAsync(cntS, 0, sizeof(int) * N_NODES, stream);
    hipMemsetAsync(cntD, 0, sizeof(int) * N_NODES, stream);
    hist_kernel<<<(E_SPARSE + 255) / 256, 256, 0, stream>>>(dstS, E_SPARSE, cntS);
    hist_kernel<<<(E_DENSE + 255) / 256, 256, 0, stream>>>(dstD, E_DENSE, cntD);
    scan_kernel<<<1, 1024, 0, stream>>>(cntS, N_NODES, rowS, curS);
    scan_kernel<<<1, 1024, 0, stream>>>(cntD, N_NODES, rowD, curD);
    scatter_kernel<<<(E_SPARSE + 255) / 256, 256, 0, stream>>>(srcS, dstS, E_SPARSE, curS, csrcS);
    scatter_kernel<<<(E_DENSE + 255) / 256, 256, 0, stream>>>(srcD, dstD, E_DENSE, curD, csrcD);

    hipMemcpyAsync(xbuf0, x_in, sizeof(float) * (size_t)N_NODES * HID,
                   hipMemcpyDeviceToDevice, stream);

    float* xc = xbuf0;
    float* xn = xbuf1;
    const int aggr_grid = (N_NODES + 3) / 4;  // 4 waves/block, 1 node/wave
    for (int l = 0; l < N_LAYERS; ++l) {
        node_mm<<<N_NODES, 64, 0, stream>>>(xc, lin_w + (size_t)l * HID * OUT_D,
                                            att_src + l * OUT_D, att_dst + l * OUT_D,
                                            h, s_src, s_dst);
        gat_aggr<<<aggr_grid, 256, 0, stream>>>(rowS, csrcS, s_src, s_dst, h,
                                                bias + l * OUT_D, xn, 0);
        gat_aggr<<<aggr_grid, 256, 0, stream>>>(rowD, csrcD, s_src, s_dst, h,
                                                bias + l * OUT_D, xn, OUT_D);
        float* t = xc; xc = xn; xn = t;
    }

    hipMemsetAsync(g, 0, sizeof(float) * (size_t)N_GRAPHS * HID, stream);
    pool<<<(N_NODES * HID + 255) / 256, 256, 0, stream>>>(xc, batch, g);
    final_lin<<<N_GRAPHS, HID, 0, stream>>>(g, fw, fb, y);
}